// Round 4
// baseline (246.547 us; speedup 1.0000x reference)
//
#include <hip/hip_runtime.h>

// VQ-VAE vector quantizer, MI355X (gfx950).
// Round 9: argmin restructured LDS-free / barrier-free.
//  - Round-8 was LDS-pipe bound (4x tile read amplification: every wave read
//    the whole 16KB B-tile for its 16 points; ~49us of DS traffic per CU).
//  - Codebook (512KB fp16 perm) fits per-XCD L2: stream B-fragments straight
//    from global (1KB/instr coalesced, L2-hit). No __syncthreads in main loop.
//  - Wave owns 64 points x 512 codes: A-frags resident (128 VGPR), top-3
//    state 16 slots. 2 waves/SIMD (VGPR-capped). Cross-half merge via 5KB LDS.
//  - finalize_kernel parallelized (was 1 thread x 256 serial fp64 loads).
//
// d_out (float32): [0,16777216) quantized; [16777216,16842752) codes; [16842752] vq_loss
//   scratch (all overwritten by gather later):
//     bytes [0, 524288)         cbh_perm (fp16, x1024)
//     bytes [1048576, 1572864)  ull minkey scratch[65536] (memset 0xFF)
//     bytes [1572864, 1835008)  int flagf[65536]
// d_ws: [0,2048) double loss_slots[256]; [2048,2052) int cnt2; [2052,2056) int cntf;
//       [4096,8192) float Bf[1024]; [8192,270336) uint flag2[65536] (n | seck<<16)

#define N_PTS    65536
#define K_CODES  1024
#define DIM      256
#define MARGIN   1.5e-4f

#define OUT_VALS  16777216
#define OUT_CODES 65536

typedef __attribute__((ext_vector_type(8))) short short8v;
typedef __attribute__((ext_vector_type(8))) _Float16 half8v;
typedef __attribute__((ext_vector_type(4))) float float4v;

// perm index (in shorts) for codebook element (r, k):
// chunk = ((r>>4)*8 + (k>>5))*4 + ((k>>3)&3); idx = chunk*128 + (r&15)*8 + (k&7)
__device__ __forceinline__ int perm_idx(int r, int k) {
  return ((((r >> 4) * 8 + (k >> 5)) * 4 + ((k >> 3) & 3)) * 128) + (r & 15) * 8 + (k & 7);
}

__device__ __forceinline__ short f2h_bits(float x) {
  union { _Float16 h; short s; } u;
  u.h = (_Float16)x;              // v_cvt_f16_f32, RTE
  return u.s;
}

// one wave per code row: Bf[r] = fl32(fp64 sum of squares of ORIGINAL cb);
// also emit fp16(1024*cb) in B-fragment-permuted order. grid 256 x 256.
__global__ void prep_cb_kernel(const float* __restrict__ cb,
                               short* __restrict__ cbh_perm,
                               float* __restrict__ Bf) {
  int r    = blockIdx.x * 4 + (threadIdx.x >> 6);
  int lane = threadIdx.x & 63;
  const float4 v = *(const float4*)(cb + (size_t)r * DIM + lane * 4);
  double s = (double)v.x * v.x + (double)v.y * v.y
           + (double)v.z * v.z + (double)v.w * v.w;
#pragma unroll
  for (int off = 32; off > 0; off >>= 1) s += __shfl_down(s, off);
  if (lane == 0) Bf[r] = (float)s;
  short4 h = make_short4(f2h_bits(v.x * 1024.0f), f2h_bits(v.y * 1024.0f),
                         f2h_bits(v.z * 1024.0f), f2h_bits(v.w * 1024.0f));
  *(short4*)(cbh_perm + perm_idx(r, lane * 4)) = h;   // (k&7)∈{0,4}: 8B aligned
}

// 512 blocks x 256 thr (4 waves). Block: 128 points x all 1024 codes.
// Wave (wp, wc): points [blk*128 + wp*64, +64), codes [wc*512, +512).
// A-frags resident; B streamed from global perm layout (L2-resident, 1KB/load).
__global__ __launch_bounds__(256, 2) void argmin_mfma_kernel(
    const float* __restrict__ z, const short* __restrict__ cbh_perm,
    const float* __restrict__ Bf, float* __restrict__ codes_out,
    int* __restrict__ cnt2, int* __restrict__ cntf,
    unsigned* __restrict__ flag2, int* __restrict__ flagf) {
  __shared__ float mv1[128][2], mv2[128][2], mv3[128][2];
  __shared__ int   mk1[128][2], mk2[128][2];
  const int t    = threadIdx.x;
  const int w    = t >> 6;
  const int l    = t & 63;
  const int quad = l >> 4;
  const int lr   = l & 15;
  const int wp   = w >> 1;          // point half
  const int wc   = w & 1;           // code half
  const int pbase = blockIdx.x * 128 + wp * 64;

  // A-fragments for 64 points: ah[p][q], lane holds A[m=lr][k=q*32+quad*8+j]
  half8v ah[4][8];
  {
    const float* zw = z + (size_t)(pbase + lr) * DIM;
#pragma unroll
    for (int p = 0; p < 4; ++p) {
      const float* zr = zw + p * 16 * DIM;
#pragma unroll
      for (int q = 0; q < 8; ++q) {
        float4 a0 = *(const float4*)(zr + q * 32 + quad * 8);
        float4 a1 = *(const float4*)(zr + q * 32 + quad * 8 + 4);
        half8v h;
        h[0] = (_Float16)a0.x; h[1] = (_Float16)a0.y;
        h[2] = (_Float16)a0.z; h[3] = (_Float16)a0.w;
        h[4] = (_Float16)a1.x; h[5] = (_Float16)a1.y;
        h[6] = (_Float16)a1.z; h[7] = (_Float16)a1.w;
        ah[p][q] = h;
      }
    }
  }

  // top-3 per point-slot s = p*4+r  (point = pbase + p*16 + quad*4 + r)
  float bv[16], sv[16], tv[16]; int bk[16], sk[16];
#pragma unroll
  for (int s = 0; s < 16; ++s) {
    bv[s] = 3.0e38f; sv[s] = 3.0e38f; tv[s] = 3.0e38f; bk[s] = 0; sk[s] = 0;
  }

  const int lane_off = quad * 128 + lr * 8;   // shorts, within a 16-code group
  for (int st = 0; st < 32; ++st) {
    const int g = wc * 32 + st;               // absolute 16-code group
    const short* bp = cbh_perm + (size_t)g * 4096 + lane_off;
    float4v acc[4] = {{0.f,0.f,0.f,0.f}, {0.f,0.f,0.f,0.f},
                      {0.f,0.f,0.f,0.f}, {0.f,0.f,0.f,0.f}};
    short8v b[8];
#pragma unroll
    for (int q = 0; q < 4; ++q) b[q] = *(const short8v*)(bp + q * 512);
#pragma unroll
    for (int q = 0; q < 4; ++q)
#pragma unroll
      for (int p = 0; p < 4; ++p)
        acc[p] = __builtin_amdgcn_mfma_f32_16x16x32_f16(ah[p][q], b[q], acc[p], 0, 0, 0);
#pragma unroll
    for (int q = 4; q < 8; ++q) b[q] = *(const short8v*)(bp + q * 512);
#pragma unroll
    for (int q = 4; q < 8; ++q)
#pragma unroll
      for (int p = 0; p < 4; ++p)
        acc[p] = __builtin_amdgcn_mfma_f32_16x16x32_f16(ah[p][q], b[q], acc[p], 0, 0, 0);

    const int kl = (g << 4) + lr;             // this lane's code (C col = lr)
    const float bkf = Bf[kl];
#pragma unroll
    for (int p = 0; p < 4; ++p)
#pragma unroll
      for (int r = 0; r < 4; ++r) {
        const int s = p * 4 + r;
        float v = fmaf(-0.001953125f, acc[p][r], bkf);   // -2/1024, exact
        bool lt1 = v < bv[s];
        bool lt2 = v < sv[s];
        // sorted-insert via min/med (bv<=sv<=tv invariant):
        tv[s] = fminf(fmaxf(v, sv[s]), tv[s]);
        sv[s] = fminf(fmaxf(v, bv[s]), sv[s]);
        bv[s] = fminf(v, bv[s]);
        sk[s] = lt1 ? bk[s] : (lt2 ? kl : sk[s]);
        bk[s] = lt1 ? kl : bk[s];
      }
  }

  // top-3 merge across the 16 col-lanes of each quad (butterfly, lex on (v,k))
#pragma unroll
  for (int mask = 1; mask < 16; mask <<= 1) {
#pragma unroll
    for (int s = 0; s < 16; ++s) {
      float ov  = __shfl_xor(bv[s], mask);
      float os  = __shfl_xor(sv[s], mask);
      float ot  = __shfl_xor(tv[s], mask);
      int   ok  = __shfl_xor(bk[s], mask);
      int   osk = __shfl_xor(sk[s], mask);
      bool win = (ov < bv[s]) || (ov == bv[s] && ok < bk[s]);
      float a1 = win ? ov : bv[s], a2 = win ? os : sv[s], a3 = win ? ot : tv[s];
      int   a1k = win ? ok : bk[s], a2k = win ? osk : sk[s];
      float b1 = win ? bv[s] : ov, b2 = win ? sv[s] : os;
      int   b1k = win ? bk[s] : ok;
      bool s2 = (a2 < b1) || (a2 == b1 && a2k < b1k);
      bv[s] = a1; bk[s] = a1k;
      sv[s] = s2 ? a2 : b1; sk[s] = s2 ? a2k : b1k;
      tv[s] = s2 ? fminf(a3, b1) : fminf(a2, b2);
    }
  }

  // publish per-(point, code-half) triples; merge halves per point
  if (lr == 0) {
#pragma unroll
    for (int p = 0; p < 4; ++p)
#pragma unroll
      for (int r = 0; r < 4; ++r) {
        int s  = p * 4 + r;
        int pt = wp * 64 + p * 16 + quad * 4 + r;
        mv1[pt][wc] = bv[s]; mv2[pt][wc] = sv[s]; mv3[pt][wc] = tv[s];
        mk1[pt][wc] = bk[s]; mk2[pt][wc] = sk[s];
      }
  }
  __syncthreads();
  if (t < 128) {
    float a1 = mv1[t][0], a2 = mv2[t][0], a3 = mv3[t][0];
    int   a1k = mk1[t][0], a2k = mk2[t][0];
    float c1 = mv1[t][1], c2 = mv2[t][1], c3 = mv3[t][1];
    int   c1k = mk1[t][1], c2k = mk2[t][1];
    bool win = (c1 < a1) || (c1 == a1 && c1k < a1k);
    float x1 = win ? c1 : a1, x2 = win ? c2 : a2, x3 = win ? c3 : a3;
    int   x1k = win ? c1k : a1k, x2k = win ? c2k : a2k;
    float y1 = win ? a1 : c1, y2 = win ? a2 : c2;
    int   y1k = win ? a1k : c1k;
    bool s2 = (x2 < y1) || (x2 == y1 && x2k < y1k);
    float f2v = s2 ? x2 : y1; int f2k = s2 ? x2k : y1k;
    float f3v = s2 ? fminf(x3, y1) : fminf(x2, y2);
    int n = blockIdx.x * 128 + t;
    codes_out[n] = (float)x1k;
    if (f3v - x1 < MARGIN) {
      int pos = atomicAdd(cntf, 1);
      flagf[pos] = n;
    } else if (f2v - x1 < MARGIN) {
      int pos = atomicAdd(cnt2, 1);
      flag2[pos] = (unsigned)n | ((unsigned)f2k << 16);
    }
  }
}

// Pair fixup: one wave per flagged row; half-wave per candidate code.
// Exact emulation: v = fl32(fl32(Sfl + Bf[k]) - 2*fl32(dot64)); tie -> lower k.
__global__ __launch_bounds__(256) void fixup_pair_kernel(
    const float* __restrict__ z, const float* __restrict__ cb,
    const float* __restrict__ Bf, const unsigned* __restrict__ flag2,
    const int* __restrict__ cnt2, float* __restrict__ codes_out) {
  const int t   = threadIdx.x;
  const int l   = t & 63;
  const int h   = l >> 5;          // 0 -> bestk, 1 -> seck
  const int sub = l & 31;          // dims sub*8 .. sub*8+7
  const int wid = blockIdx.x * 4 + (t >> 6);
  const int nw  = gridDim.x * 4;
  const int cnt = *cnt2;
  for (int i = wid; i < cnt; i += nw) {
    const unsigned rec = flag2[i];
    const int n  = rec & 0xFFFF;
    const int k2 = rec >> 16;
    const int k1 = (int)codes_out[n];
    const int k  = h ? k2 : k1;
    const float* zr = z + (size_t)n * DIM + sub * 8;
    const float* cr = cb + (size_t)k * DIM + sub * 8;
    const float4 za = *(const float4*)(zr);
    const float4 zb = *(const float4*)(zr + 4);
    const float4 ca = *(const float4*)(cr);
    const float4 cv = *(const float4*)(cr + 4);
    double s = (double)za.x*za.x + (double)za.y*za.y + (double)za.z*za.z + (double)za.w*za.w
             + (double)zb.x*zb.x + (double)zb.y*zb.y + (double)zb.z*zb.z + (double)zb.w*zb.w;
    double d = (double)za.x*ca.x + (double)za.y*ca.y + (double)za.z*ca.z + (double)za.w*ca.w
             + (double)zb.x*cv.x + (double)zb.y*cv.y + (double)zb.z*cv.z + (double)zb.w*cv.w;
#pragma unroll
    for (int m = 1; m < 32; m <<= 1) {
      s += __shfl_xor(s, m);
      d += __shfl_xor(d, m);
    }
    const float Sfl = (float)s;
    const float T1  = Sfl + Bf[k];
    const float v   = T1 - 2.0f * (float)d;
    const float vo  = __shfl_xor(v, 32);
    const int   ko  = __shfl_xor(k, 32);
    const bool keep = (v < vo) || (v == vo && k < ko);
    if (l == 0) codes_out[n] = (float)(keep ? k : ko);
  }
}

// Full rescan for rows with 3+ candidates inside MARGIN (expected ~tens).
// 4 blocks per row (quarter q = codes q*256..q*256+255); wave handles 64.
// Cross-block merge via atomicMin on (f32-bits<<32 | k); v>0 always
// (d ~ ||z||^2 ~ 100..500) so the uint order of the float bits is monotone.
__global__ __launch_bounds__(256) void fixup_full_kernel(
    const float* __restrict__ z, const float* __restrict__ cb,
    const float* __restrict__ Bf, const int* __restrict__ flagf,
    const int* __restrict__ cntf, unsigned long long* __restrict__ scratch) {
  __shared__ float vred[4];
  __shared__ int   kred[4];
  const int t = threadIdx.x;
  const int w = t >> 6;
  const int l = t & 63;
  const int cnt = *cntf;
  for (int ib = blockIdx.x; (ib >> 2) < cnt; ib += gridDim.x) {
    const int i = ib >> 2, q = ib & 3;
    const int n = flagf[i];
    const float4 zv = *(const float4*)(z + (size_t)n * DIM + l * 4);
    double s = (double)zv.x*zv.x + (double)zv.y*zv.y
             + (double)zv.z*zv.z + (double)zv.w*zv.w;
#pragma unroll
    for (int off = 32; off > 0; off >>= 1) s += __shfl_xor(s, off);
    const float Sfl = (float)s;
    float bvv = 3.0e38f; int bkk = 0;
    const int kbase = q * 256 + w * 64;
#pragma unroll 4
    for (int k0 = 0; k0 < 64; ++k0) {
      const int k = kbase + k0;
      const float4 cv = *(const float4*)(cb + (size_t)k * DIM + l * 4);
      double d = (double)zv.x*cv.x + (double)zv.y*cv.y
               + (double)zv.z*cv.z + (double)zv.w*cv.w;
#pragma unroll
      for (int off = 32; off > 0; off >>= 1) d += __shfl_xor(d, off);
      float T1 = Sfl + Bf[k];
      float v  = T1 - 2.0f * (float)d;
      if (v < bvv) { bvv = v; bkk = k; }   // ascending k -> keeps lowest on tie
    }
    __syncthreads();
    if (l == 0) { vred[w] = bvv; kred[w] = bkk; }
    __syncthreads();
    if (t == 0) {
      float fv = vred[0]; int fk = kred[0];
#pragma unroll
      for (int j = 1; j < 4; ++j) {
        float v2 = vred[j]; int kk = kred[j];
        if (v2 < fv || (v2 == fv && kk < fk)) { fv = v2; fk = kk; }
      }
      unsigned long long key =
          ((unsigned long long)__float_as_uint(fv) << 32) | (unsigned)fk;
      atomicMin(&scratch[n], key);
    }
  }
}

__global__ void fixup_write_kernel(const int* __restrict__ flagf,
                                   const int* __restrict__ cntf,
                                   const unsigned long long* __restrict__ scratch,
                                   float* __restrict__ codes_out) {
  int i = blockIdx.x * 256 + threadIdx.x;
  if (i < *cntf) {
    int n = flagf[i];
    codes_out[n] = (float)(unsigned)(scratch[n] & 0xFFFFFFFFull);
  }
}

__global__ void gather_loss_kernel(const float* __restrict__ z,
                                   const float* __restrict__ cb,
                                   float* __restrict__ out,
                                   const float* __restrict__ codes_f,
                                   double* __restrict__ loss_slots) {
  int gid = blockIdx.x * 256 + threadIdx.x;
  int n   = gid >> 6;
  int d4  = (gid & 63) * 4;
  int c   = (int)codes_f[n];
  float4 q  = *(const float4*)(cb + (size_t)c * DIM + d4);
  float4 zv = *(const float4*)(z + (size_t)gid * 4);
  *(float4*)(out + (size_t)gid * 4) = q;
  float dx = q.x - zv.x, dy = q.y - zv.y, dz = q.z - zv.z, dw = q.w - zv.w;
  float s = dx * dx + dy * dy + dz * dz + dw * dw;
#pragma unroll
  for (int off = 32; off > 0; off >>= 1) s += __shfl_down(s, off);
  __shared__ float wsum[4];
  int lane = threadIdx.x & 63, wv = threadIdx.x >> 6;
  if (lane == 0) wsum[wv] = s;
  __syncthreads();
  if (threadIdx.x == 0) {
    float tot = wsum[0] + wsum[1] + wsum[2] + wsum[3];
    atomicAdd(&loss_slots[blockIdx.x & 255], (double)tot);
  }
}

__global__ void finalize_kernel(const double* __restrict__ loss_slots,
                                float* __restrict__ out_loss) {
  const int t = threadIdx.x;          // 256 threads
  double s = loss_slots[t];
#pragma unroll
  for (int off = 32; off > 0; off >>= 1) s += __shfl_down(s, off);
  __shared__ double ws[4];
  if ((t & 63) == 0) ws[t >> 6] = s;
  __syncthreads();
  if (t == 0) {
    double tot = ws[0] + ws[1] + ws[2] + ws[3];
    out_loss[0] = (float)(1.25 * tot / (double)(N_PTS * (size_t)DIM));
  }
}

extern "C" void kernel_launch(void* const* d_in, const int* in_sizes, int n_in,
                              void* d_out, int out_size, void* d_ws, size_t ws_size,
                              hipStream_t stream) {
  const float* z  = (const float*)d_in[0];
  const float* cb = (const float*)d_in[1];
  float* out = (float*)d_out;
  double* loss_slots = (double*)d_ws;
  int*      cnt2  = (int*)((char*)d_ws + 2048);
  int*      cntf  = (int*)((char*)d_ws + 2052);
  float*    Bf    = (float*)((char*)d_ws + 4096);
  unsigned* flag2 = (unsigned*)((char*)d_ws + 8192);
  short* cbh_perm = (short*)d_out;            // scratch in out[0:524288) bytes
  unsigned long long* scratch = (unsigned long long*)((char*)d_out + 1048576);
  int*   flagf    = (int*)((char*)d_out + 1572864);

  hipMemsetAsync(d_ws, 0, 4096, stream);
  hipMemsetAsync((char*)d_out + 1048576, 0xFF, 524288, stream);
  prep_cb_kernel<<<K_CODES / 4, 256, 0, stream>>>(cb, cbh_perm, Bf);
  argmin_mfma_kernel<<<N_PTS / 128, 256, 0, stream>>>(
      z, cbh_perm, Bf, out + OUT_VALS, cnt2, cntf, flag2, flagf);
  fixup_pair_kernel<<<1024, 256, 0, stream>>>(z, cb, Bf, flag2, cnt2,
                                              out + OUT_VALS);
  fixup_full_kernel<<<2048, 256, 0, stream>>>(z, cb, Bf, flagf, cntf, scratch);
  fixup_write_kernel<<<256, 256, 0, stream>>>(flagf, cntf, scratch,
                                              out + OUT_VALS);
  gather_loss_kernel<<<(N_PTS * DIM / 4) / 256, 256, 0, stream>>>(
      z, cb, out, out + OUT_VALS, loss_slots);
  finalize_kernel<<<1, 256, 0, stream>>>(loss_slots, out + OUT_VALS + OUT_CODES);
}

// Round 5
// 201.150 us; speedup vs baseline: 1.2257x; 1.2257x over previous
//
#include <hip/hip_runtime.h>

// VQ-VAE vector quantizer, MI355X (gfx950).
// Round 10:
//  - argmin back to LDS-staged r8 structure (103us) + the m97 ladder step:
//    global_load_lds(16B) async staging, double-buffered (stage t+1 while
//    computing t, one barrier/iter), 4 blocks/CU (occ 38->50%).
//  - gather/loss fused away: argmin accumulates loss = sum(bestv) (error
//    ~1e-9 on the final scalar) and scatters quantized rows for n>=4096
//    (rows <4096 overlap d_out scratch; written by small_gather at the end).
//    fixup_pair / fixup_write apply per-row loss deltas + row rewrites.
//  - memsets folded into prep. Dispatches 9 -> 7.
//
// d_out scratch (bytes, all consumed before small_gather / overwritten later):
//   [0,524288) cbh_perm | [524288,786432) bv2a | [786432,1048576) bvfa
//   [1048576,1572864) ull minkey scratch | [1572864,1835008) flagf
// d_ws: [0,2048) double loss_slots[256]; [2048,2052) cnt2; [2052,2056) cntf;
//       [4096,8192) float Bf[1024]; [8192,270336) uint flag2 (n | seck<<16)

#define N_PTS    65536
#define K_CODES  1024
#define DIM      256
#define MARGIN   1.5e-4f
#define WSKIP    4096

#define OUT_VALS  16777216
#define OUT_CODES 65536

typedef __attribute__((ext_vector_type(8))) short short8v;
typedef __attribute__((ext_vector_type(8))) _Float16 half8v;
typedef __attribute__((ext_vector_type(4))) float float4v;

// perm index (in shorts) for codebook element (r=code, k=dim):
// chunk = ((r>>4)*8 + (k>>5))*4 + ((k>>3)&3); idx = chunk*128 + (r&15)*8 + (k&7)
__device__ __forceinline__ int perm_idx(int r, int k) {
  return ((((r >> 4) * 8 + (k >> 5)) * 4 + ((k >> 3) & 3)) * 128) + (r & 15) * 8 + (k & 7);
}

__device__ __forceinline__ short f2h_bits(float x) {
  union { _Float16 h; short s; } u;
  u.h = (_Float16)x;              // v_cvt_f16_f32, RTE
  return u.s;
}

__device__ __forceinline__ void gload16(const void* g, void* l) {
  __builtin_amdgcn_global_load_lds(
      (const __attribute__((address_space(1))) unsigned*)g,
      (__attribute__((address_space(3))) unsigned*)l, 16, 0, 0);
}

// one wave per code row: Bf[r] = fl32(fp64 sum sq of ORIGINAL cb); emit
// fp16(1024*cb) in B-fragment-permuted order. Also init ws header + scratch.
__global__ void prep_cb_kernel(const float* __restrict__ cb,
                               short* __restrict__ cbh_perm,
                               float* __restrict__ Bf,
                               unsigned long long* __restrict__ scratch,
                               unsigned long long* __restrict__ ws0) {
  const int gid = blockIdx.x * 256 + threadIdx.x;
  scratch[gid] = ~0ull;                       // 65536 minkeys
  if (gid < 512) ws0[gid] = 0ull;             // loss_slots + cnt2/cntf
  int r    = blockIdx.x * 4 + (threadIdx.x >> 6);
  int lane = threadIdx.x & 63;
  const float4 v = *(const float4*)(cb + (size_t)r * DIM + lane * 4);
  double s = (double)v.x * v.x + (double)v.y * v.y
           + (double)v.z * v.z + (double)v.w * v.w;
#pragma unroll
  for (int off = 32; off > 0; off >>= 1) s += __shfl_down(s, off);
  if (lane == 0) Bf[r] = (float)s;
  short4 h = make_short4(f2h_bits(v.x * 1024.0f), f2h_bits(v.y * 1024.0f),
                         f2h_bits(v.z * 1024.0f), f2h_bits(v.w * 1024.0f));
  *(short4*)(cbh_perm + perm_idx(r, lane * 4)) = h;   // 8B aligned
}

// 1024 blocks x 256 thr (4 waves). Block: 64 points x all 1024 codes.
// Wave w: 16 points, A-frags resident (fp16). Tiles of 32 codes double-
// buffered in LDS via global_load_lds; one barrier per tile.
__global__ __launch_bounds__(256, 4) void argmin_mfma_kernel(
    const float* __restrict__ z, const float* __restrict__ cb,
    const short* __restrict__ cbh_perm,
    const float* __restrict__ Bf, float* __restrict__ outq,
    float* __restrict__ codes_out,
    int* __restrict__ cnt2, int* __restrict__ cntf,
    unsigned* __restrict__ flag2, int* __restrict__ flagf,
    float* __restrict__ bv2a, float* __restrict__ bvfa,
    double* __restrict__ loss_slots) {
  __shared__ __align__(16) short lbuf[2][8192];   // 2 x 16 KB tiles
  __shared__ double wls[4];
  const int t    = threadIdx.x;
  const int w    = t >> 6;
  const int l    = t & 63;
  const int quad = l >> 4;
  const int lr   = l & 15;
  const int m0   = blockIdx.x * 64;

  // stage tile 0 early (latency hides under A-frag load/convert)
  {
    const char* src = (const char*)cbh_perm;
    char* dst = (char*)&lbuf[0][0];
#pragma unroll
    for (int i = 0; i < 4; ++i)
      gload16(src + t * 16 + i * 4096, dst + t * 16 + i * 4096);
  }

  // A-fragments: lane holds A[m=lr][k=q*32+quad*8+j], fp16 (z unscaled)
  half8v ah[8];
  {
    const float* zrow = z + (size_t)(m0 + w * 16 + lr) * DIM;
#pragma unroll
    for (int q = 0; q < 8; ++q) {
      float4 p0 = *(const float4*)(zrow + q * 32 + quad * 8);
      float4 p1 = *(const float4*)(zrow + q * 32 + quad * 8 + 4);
      half8v h;
      h[0] = (_Float16)p0.x; h[1] = (_Float16)p0.y;
      h[2] = (_Float16)p0.z; h[3] = (_Float16)p0.w;
      h[4] = (_Float16)p1.x; h[5] = (_Float16)p1.y;
      h[6] = (_Float16)p1.z; h[7] = (_Float16)p1.w;
      ah[q] = h;
    }
  }

  float bestv[4], secv[4], thirdv[4]; int bestk[4], seck[4];
#pragma unroll
  for (int r = 0; r < 4; ++r) {
    bestv[r] = 3.0e38f; secv[r] = 3.0e38f; thirdv[r] = 3.0e38f;
    bestk[r] = 0; seck[r] = 0;
  }

  __syncthreads();          // full drain: tile 0 resident
  int cur = 0;
  for (int it = 0; it < 32; ++it) {
    if (it < 31) {          // prefetch tile it+1 into the other buffer
      const char* src = (const char*)cbh_perm + (size_t)(it + 1) * 16384;
      char* dst = (char*)&lbuf[cur ^ 1][0];
#pragma unroll
      for (int i = 0; i < 4; ++i)
        gload16(src + t * 16 + i * 4096, dst + t * 16 + i * 4096);
    }
    const int c0 = it * 32;
#pragma unroll
    for (int st = 0; st < 2; ++st) {
      float4v acc = {0.f, 0.f, 0.f, 0.f};
#pragma unroll
      for (int q = 0; q < 8; ++q) {
        // B-frag: lane holds B[k=quad*8+j][n=lr] == cb'[n][k]
        half8v b = *(const half8v*)(&lbuf[cur][(st * 8 + q) * 512 + quad * 128 + lr * 8]);
        acc = __builtin_amdgcn_mfma_f32_16x16x32_f16(ah[q], b, acc, 0, 0, 0);
      }
      const int k = c0 + st * 16 + lr;       // this lane's code (C col = lr)
      const float bkf = Bf[k];
#pragma unroll
      for (int r = 0; r < 4; ++r) {          // C row = quad*4 + r (point)
        float v = fmaf(-0.001953125f, acc[r], bkf);   // -2/1024, exact
        bool lt1 = v < bestv[r];
        bool lt2 = v < secv[r];
        thirdv[r] = fminf(fmaxf(v, secv[r]), thirdv[r]);   // med3
        secv[r]   = fminf(fmaxf(v, bestv[r]), secv[r]);    // med3
        bestv[r]  = fminf(v, bestv[r]);
        seck[r]   = lt1 ? bestk[r] : (lt2 ? k : seck[r]);
        bestk[r]  = lt1 ? k : bestk[r];
      }
    }
    __syncthreads();        // drains vmcnt: tile it+1 landed; readers done
    cur ^= 1;
  }

  // top-3 merge across the 16 col-lanes of each quad (butterfly)
#pragma unroll
  for (int mask = 1; mask < 16; mask <<= 1) {
#pragma unroll
    for (int r = 0; r < 4; ++r) {
      float ov  = __shfl_xor(bestv[r], mask);
      float os  = __shfl_xor(secv[r], mask);
      float ot  = __shfl_xor(thirdv[r], mask);
      int   ok  = __shfl_xor(bestk[r], mask);
      int   osk = __shfl_xor(seck[r], mask);
      bool win = (ov < bestv[r]) || (ov == bestv[r] && ok < bestk[r]);
      float a1 = win ? ov : bestv[r], a2 = win ? os : secv[r], a3 = win ? ot : thirdv[r];
      int   a1k = win ? ok : bestk[r], a2k = win ? osk : seck[r];
      float b1 = win ? bestv[r] : ov, b2 = win ? secv[r] : os;
      int   b1k = win ? bestk[r] : ok;
      bool s2 = (a2 < b1) || (a2 == b1 && a2k < b1k);
      bestv[r] = a1; bestk[r] = a1k;
      secv[r] = s2 ? a2 : b1; seck[r] = s2 ? a2k : b1k;
      thirdv[r] = s2 ? fminf(a3, b1) : fminf(a2, b2);
    }
  }

  // fused quantized scatter (rows < WSKIP deferred: they overlap scratch)
  if (m0 >= WSKIP) {
#pragma unroll
    for (int p = 0; p < 16; ++p) {
      int c = __shfl(bestk[p & 3], (p >> 2) << 4);   // quad (p>>2), slot (p&3)
      int n = m0 + w * 16 + p;
      *(float4*)(outq + (size_t)n * DIM + l * 4) =
          *(const float4*)(cb + (size_t)c * DIM + l * 4);
    }
  }

  // fused loss: sum of bestv over the wave's 16 points
  double ls = 0.0;
  if (lr == 0)
    ls = (double)bestv[0] + (double)bestv[1] + (double)bestv[2] + (double)bestv[3];
  ls += __shfl_down(ls, 16);
  ls += __shfl_down(ls, 32);
  if (l == 0) wls[w] = ls;

  if (lr == 0) {
#pragma unroll
    for (int r = 0; r < 4; ++r) {
      int n = m0 + w * 16 + quad * 4 + r;
      codes_out[n] = (float)bestk[r];
      if (thirdv[r] - bestv[r] < MARGIN) {
        int pos = atomicAdd(cntf, 1);
        flagf[pos] = n; bvfa[pos] = bestv[r];
      } else if (secv[r] - bestv[r] < MARGIN) {
        int pos = atomicAdd(cnt2, 1);
        flag2[pos] = (unsigned)n | ((unsigned)seck[r] << 16);
        bv2a[pos] = bestv[r];
      }
    }
  }
  __syncthreads();
  if (t == 0)
    atomicAdd(&loss_slots[blockIdx.x & 255], wls[0] + wls[1] + wls[2] + wls[3]);
}

// Pair fixup: one wave per flagged row; half-wave per candidate code.
// Exact emulation: v = fl32(fl32(Sfl + Bf[k]) - 2*fl32(dot64)); tie -> lower k.
// Applies loss delta (exact - approx) and rewrites the quantized row if changed.
__global__ __launch_bounds__(256) void fixup_pair_kernel(
    const float* __restrict__ z, const float* __restrict__ cb,
    const float* __restrict__ Bf, const unsigned* __restrict__ flag2,
    const int* __restrict__ cnt2, const float* __restrict__ bv2a,
    float* __restrict__ codes_out, float* __restrict__ outq,
    double* __restrict__ loss_slots) {
  const int t   = threadIdx.x;
  const int l   = t & 63;
  const int h   = l >> 5;          // 0 -> bestk, 1 -> seck
  const int sub = l & 31;          // dims sub*8 .. sub*8+7
  const int wid = blockIdx.x * 4 + (t >> 6);
  const int nw  = gridDim.x * 4;
  const int cnt = *cnt2;
  for (int i = wid; i < cnt; i += nw) {
    const unsigned rec = flag2[i];
    const int n  = rec & 0xFFFF;
    const int k2 = rec >> 16;
    const int k1 = (int)codes_out[n];
    const int k  = h ? k2 : k1;
    const float* zr = z + (size_t)n * DIM + sub * 8;
    const float* cr = cb + (size_t)k * DIM + sub * 8;
    const float4 za = *(const float4*)(zr);
    const float4 zb = *(const float4*)(zr + 4);
    const float4 ca = *(const float4*)(cr);
    const float4 cv = *(const float4*)(cr + 4);
    double s = (double)za.x*za.x + (double)za.y*za.y + (double)za.z*za.z + (double)za.w*za.w
             + (double)zb.x*zb.x + (double)zb.y*zb.y + (double)zb.z*zb.z + (double)zb.w*zb.w;
    double d = (double)za.x*ca.x + (double)za.y*ca.y + (double)za.z*ca.z + (double)za.w*ca.w
             + (double)zb.x*cv.x + (double)zb.y*cv.y + (double)zb.z*cv.z + (double)zb.w*cv.w;
#pragma unroll
    for (int m = 1; m < 32; m <<= 1) {
      s += __shfl_xor(s, m);
      d += __shfl_xor(d, m);
    }
    const float Sfl = (float)s;
    const float T1  = Sfl + Bf[k];
    const float v   = T1 - 2.0f * (float)d;
    const float vo  = __shfl_xor(v, 32);
    const int   ko  = __shfl_xor(k, 32);
    const bool keep = (v < vo) || (v == vo && k < ko);
    const float vmin = keep ? v : vo;
    const int   kf   = keep ? k : ko;       // consistent across both halves
    if (l == 0) {
      codes_out[n] = (float)kf;
      atomicAdd(&loss_slots[n & 255], (double)(vmin - bv2a[i]));
    }
    if (kf != k1 && n >= WSKIP)
      *(float4*)(outq + (size_t)n * DIM + l * 4) =
          *(const float4*)(cb + (size_t)kf * DIM + l * 4);
  }
}

// Full rescan for rows with 3+ candidates inside MARGIN (expected ~tens).
// 4 blocks per row; cross-block merge via atomicMin on (f32-bits<<32 | k).
__global__ __launch_bounds__(256) void fixup_full_kernel(
    const float* __restrict__ z, const float* __restrict__ cb,
    const float* __restrict__ Bf, const int* __restrict__ flagf,
    const int* __restrict__ cntf, unsigned long long* __restrict__ scratch) {
  __shared__ float vred[4];
  __shared__ int   kred[4];
  const int t = threadIdx.x;
  const int w = t >> 6;
  const int l = t & 63;
  const int cnt = *cntf;
  for (int ib = blockIdx.x; (ib >> 2) < cnt; ib += gridDim.x) {
    const int i = ib >> 2, q = ib & 3;
    const int n = flagf[i];
    const float4 zv = *(const float4*)(z + (size_t)n * DIM + l * 4);
    double s = (double)zv.x*zv.x + (double)zv.y*zv.y
             + (double)zv.z*zv.z + (double)zv.w*zv.w;
#pragma unroll
    for (int off = 32; off > 0; off >>= 1) s += __shfl_xor(s, off);
    const float Sfl = (float)s;
    float bvv = 3.0e38f; int bkk = 0;
    const int kbase = q * 256 + w * 64;
#pragma unroll 4
    for (int k0 = 0; k0 < 64; ++k0) {
      const int k = kbase + k0;
      const float4 cv = *(const float4*)(cb + (size_t)k * DIM + l * 4);
      double d = (double)zv.x*cv.x + (double)zv.y*cv.y
               + (double)zv.z*cv.z + (double)zv.w*cv.w;
#pragma unroll
      for (int off = 32; off > 0; off >>= 1) d += __shfl_xor(d, off);
      float T1 = Sfl + Bf[k];
      float v  = T1 - 2.0f * (float)d;
      if (v < bvv) { bvv = v; bkk = k; }   // ascending k -> lowest on tie
    }
    __syncthreads();
    if (l == 0) { vred[w] = bvv; kred[w] = bkk; }
    __syncthreads();
    if (t == 0) {
      float fv = vred[0]; int fk = kred[0];
#pragma unroll
      for (int j = 1; j < 4; ++j) {
        float v2 = vred[j]; int kk = kred[j];
        if (v2 < fv || (v2 == fv && kk < fk)) { fv = v2; fk = kk; }
      }
      unsigned long long key =
          ((unsigned long long)__float_as_uint(fv) << 32) | (unsigned)fk;
      atomicMin(&scratch[n], key);
    }
  }
}

// Resolve full rows: wave per row; codes + loss delta + row rewrite.
__global__ __launch_bounds__(256) void fixup_write_kernel(
    const int* __restrict__ flagf, const int* __restrict__ cntf,
    const unsigned long long* __restrict__ scratch,
    const float* __restrict__ bvfa, const float* __restrict__ cb,
    float* __restrict__ codes_out, float* __restrict__ outq,
    double* __restrict__ loss_slots) {
  const int t = threadIdx.x, l = t & 63;
  const int wid = blockIdx.x * 4 + (t >> 6);
  const int nw  = gridDim.x * 4;
  const int cnt = *cntf;
  for (int i = wid; i < cnt; i += nw) {
    const int n = flagf[i];
    const unsigned long long key = scratch[n];
    const int   fk = (int)(unsigned)(key & 0xFFFFFFFFull);
    const float fv = __uint_as_float((unsigned)(key >> 32));
    const int   k1 = (int)codes_out[n];
    if (l == 0) {
      codes_out[n] = (float)fk;
      atomicAdd(&loss_slots[n & 255], (double)(fv - bvfa[i]));
    }
    if (fk != k1 && n >= WSKIP)
      *(float4*)(outq + (size_t)n * DIM + l * 4) =
          *(const float4*)(cb + (size_t)fk * DIM + l * 4);
  }
}

// Rows [0, WSKIP): scatter cb[codes[n]] after all fixups (scratch now dead).
__global__ void small_gather_kernel(const float* __restrict__ cb,
                                    const float* __restrict__ codes_f,
                                    float* __restrict__ outq) {
  int gid = blockIdx.x * 256 + threadIdx.x;
  int n = gid >> 6, l = gid & 63;
  int c = (int)codes_f[n];
  *(float4*)(outq + (size_t)n * DIM + l * 4) =
      *(const float4*)(cb + (size_t)c * DIM + l * 4);
}

__global__ void finalize_kernel(const double* __restrict__ loss_slots,
                                float* __restrict__ out_loss) {
  const int t = threadIdx.x;          // 256 threads
  double s = loss_slots[t];
#pragma unroll
  for (int off = 32; off > 0; off >>= 1) s += __shfl_down(s, off);
  __shared__ double ws[4];
  if ((t & 63) == 0) ws[t >> 6] = s;
  __syncthreads();
  if (t == 0) {
    double tot = ws[0] + ws[1] + ws[2] + ws[3];
    out_loss[0] = (float)(1.25 * tot / (double)(N_PTS * (size_t)DIM));
  }
}

extern "C" void kernel_launch(void* const* d_in, const int* in_sizes, int n_in,
                              void* d_out, int out_size, void* d_ws, size_t ws_size,
                              hipStream_t stream) {
  const float* z  = (const float*)d_in[0];
  const float* cb = (const float*)d_in[1];
  float* out = (float*)d_out;
  double* loss_slots = (double*)d_ws;
  int*      cnt2  = (int*)((char*)d_ws + 2048);
  int*      cntf  = (int*)((char*)d_ws + 2052);
  float*    Bf    = (float*)((char*)d_ws + 4096);
  unsigned* flag2 = (unsigned*)((char*)d_ws + 8192);
  short* cbh_perm = (short*)d_out;                                   // [0,512K)
  float* bv2a     = (float*)((char*)d_out + 524288);
  float* bvfa     = (float*)((char*)d_out + 786432);
  unsigned long long* scratch = (unsigned long long*)((char*)d_out + 1048576);
  int*   flagf    = (int*)((char*)d_out + 1572864);

  prep_cb_kernel<<<K_CODES / 4, 256, 0, stream>>>(
      cb, cbh_perm, Bf, scratch, (unsigned long long*)d_ws);
  argmin_mfma_kernel<<<N_PTS / 64, 256, 0, stream>>>(
      z, cb, cbh_perm, Bf, out, out + OUT_VALS, cnt2, cntf, flag2, flagf,
      bv2a, bvfa, loss_slots);
  fixup_pair_kernel<<<1024, 256, 0, stream>>>(
      z, cb, Bf, flag2, cnt2, bv2a, out + OUT_VALS, out, loss_slots);
  fixup_full_kernel<<<2048, 256, 0, stream>>>(z, cb, Bf, flagf, cntf, scratch);
  fixup_write_kernel<<<64, 256, 0, stream>>>(
      flagf, cntf, scratch, bvfa, cb, out + OUT_VALS, out, loss_slots);
  small_gather_kernel<<<WSKIP * 64 / 256, 256, 0, stream>>>(
      cb, out + OUT_VALS, out);
  finalize_kernel<<<1, 256, 0, stream>>>(loss_slots, out + OUT_VALS + OUT_CODES);
}